// Round 3
// baseline (268.582 us; speedup 1.0000x reference)
//
#include <hip/hip_runtime.h>
#include <cstdint>
#include <cstddef>

typedef unsigned short u16;
typedef __attribute__((ext_vector_type(8))) __bf16 bf16x8;
typedef __attribute__((ext_vector_type(4))) float f32x4;

__device__ __forceinline__ u16 f2bf(float f) {
  unsigned u = __float_as_uint(f);
  u += 0x7FFFu + ((u >> 16) & 1u);   // round-to-nearest-even
  return (u16)(u >> 16);
}

__device__ __forceinline__ void async16(u16* lds, const u16* g) {
  __builtin_amdgcn_global_load_lds(
      (const __attribute__((address_space(1))) unsigned int*)g,
      (__attribute__((address_space(3))) unsigned int*)lds, 16, 0, 0);
}

// ---------------- TT weight expansion --------------
__global__ void tt_stage1(const float* __restrict__ gA, const float* __restrict__ gB,
                          float* __restrict__ B12,
                          int I2, int O1, int O2, int R1, int R2, int total) {
  int idx = blockIdx.x * 256 + threadIdx.x;
  if (idx >= total) return;
  int r2 = idx % R2; int t = idx / R2;
  int o2 = t % O2; t /= O2;
  int o1 = t % O1; t /= O1;
  int i2 = t % I2; int i1 = t / I2;
  float s = 0.f;
  for (int r1 = 0; r1 < R1; ++r1)
    s += gA[(i1 * O1 + o1) * R1 + r1] * gB[((r1 * I2 + i2) * O2 + o2) * R2 + r2];
  B12[idx] = s;
}

__global__ void tt_stage2(const float* __restrict__ B12, const float* __restrict__ gC,
                          float* __restrict__ B123,
                          int I3, int O3, int R2, int R3, int O12, int O123, int total) {
  int idx = blockIdx.x * 256 + threadIdx.x;
  if (idx >= total) return;
  int r3 = idx % R3; int t = idx / R3;
  int fo = t % O123; int fi = t / O123;
  int o3 = fo % O3; int fo12 = fo / O3;
  int i3 = fi % I3; int fi12 = fi / I3;
  float s = 0.f;
  for (int r2 = 0; r2 < R2; ++r2)
    s += B12[(fi12 * O12 + fo12) * R2 + r2] * gC[((r2 * I3 + i3) * O3 + o3) * R3 + r3];
  B123[idx] = s;
}

// Vectorized stage3: one thread computes all I4 contiguous `in` for one (out, fi123).
template <int I4>
__global__ void tt_stage3v(const float* __restrict__ B123, const float* __restrict__ gD,
                           u16* __restrict__ Wt,
                           int O4, int O123, int Kin, int P) {
  int idx = blockIdx.x * 256 + threadIdx.x;
  if (idx >= P) return;
  const int fiCnt = Kin / I4;
  int fi123 = idx % fiCnt;
  int out = idx / fiCnt;
  int o4 = out % O4, fo123 = out / O4;
  const float* bp = B123 + (size_t)(fi123 * O123 + fo123) * 12;
  float b[12];
#pragma unroll
  for (int r = 0; r < 12; ++r) b[r] = bp[r];
  u16 vals[I4];
#pragma unroll
  for (int i4 = 0; i4 < I4; ++i4) {
    float s = 0.f;
#pragma unroll
    for (int r = 0; r < 12; ++r)
      s += b[r] * gD[(r * I4 + i4) * O4 + o4];
    vals[i4] = f2bf(s);
  }
  uint4* dst = (uint4*)(Wt + (size_t)out * Kin + fi123 * I4);
  const uint4* src = (const uint4*)vals;
#pragma unroll
  for (int c = 0; c < I4 / 8; ++c) dst[c] = src[c];
}

// Fused: x(f32)->bf16 AND out = bias2 broadcast (atomic GEMM2 accumulates on top).
// Both index spaces are 786432 float4-groups.
__global__ void prep(const float4* __restrict__ x4, ushort4* __restrict__ xb4,
                     const float4* __restrict__ b4, float4* __restrict__ out4,
                     int n4, int bn4) {
  int i = blockIdx.x * 256 + threadIdx.x;
  if (i < n4) {
    float4 v = x4[i];
    ushort4 o;
    o.x = f2bf(v.x); o.y = f2bf(v.y); o.z = f2bf(v.z); o.w = f2bf(v.w);
    xb4[i] = o;
    out4[i] = b4[i % bn4];
  }
}

// ---------------- bf16 MFMA GEMM, C = A(MxK) * Bt(NxK)^T ----------------
// BK=64 via two 128x32 LDS planes per operand (keeps verified per-plane
// staging + fragment layout; global_load_lds needs contiguous lane mapping).
// Halves barrier count per K vs BK=32.
template <bool FUSE_GELU, bool ATOMIC>
__global__ __launch_bounds__(256, 2)
void gemm_bt(const u16* __restrict__ A, const u16* __restrict__ Bt,
             const float* __restrict__ bias, u16* __restrict__ Hout,
             float* __restrict__ Fout, int N, int K, int klen) {
  __shared__ __align__(16) u16 As[2][128 * 32];
  __shared__ __align__(16) u16 Bs[2][128 * 32];
  const int tid = threadIdx.x;
  const int bm = blockIdx.x, bn = blockIdx.y;
  const int wave = tid >> 6, lane = tid & 63;
  const int wm = (wave & 1) * 64, wn = (wave >> 1) * 64;
  const int lr = lane & 15, lq = lane >> 4;

  const int srow = tid >> 2;           // 0..63
  const int scol = (tid & 3) * 8;      // 0,8,16,24
  const u16* Ag = A + (size_t)(bm * 128 + srow) * K + scol;
  const u16* Bg = Bt + (size_t)(bn * 128 + srow) * K + scol;
  u16* AsW = &As[0][0] + tid * 8;
  u16* BsW = &Bs[0][0] + tid * 8;

  f32x4 acc[4][4];
#pragma unroll
  for (int i = 0; i < 4; i++)
#pragma unroll
    for (int j = 0; j < 4; j++) acc[i][j] = (f32x4){0.f, 0.f, 0.f, 0.f};

  const int kbeg = blockIdx.z * klen;
  const int kend = kbeg + klen;
  for (int k0 = kbeg; k0 < kend; k0 += 64) {
#pragma unroll
    for (int p = 0; p < 2; p++) {
      async16(AsW + p * 4096,        Ag + k0 + p * 32);
      async16(AsW + p * 4096 + 2048, Ag + k0 + p * 32 + (size_t)64 * K);
      async16(BsW + p * 4096,        Bg + k0 + p * 32);
      async16(BsW + p * 4096 + 2048, Bg + k0 + p * 32 + (size_t)64 * K);
    }
    __syncthreads();
    bf16x8 af[2][4], bfr[2][4];
#pragma unroll
    for (int p = 0; p < 2; p++) {
#pragma unroll
      for (int i = 0; i < 4; i++)
        af[p][i] = *(const bf16x8*)(&As[p][0] + (wm + i * 16 + lr) * 32 + lq * 8);
#pragma unroll
      for (int j = 0; j < 4; j++)
        bfr[p][j] = *(const bf16x8*)(&Bs[p][0] + (wn + j * 16 + lr) * 32 + lq * 8);
    }
#pragma unroll
    for (int p = 0; p < 2; p++)
#pragma unroll
      for (int i = 0; i < 4; i++)
#pragma unroll
        for (int j = 0; j < 4; j++)
          acc[i][j] = __builtin_amdgcn_mfma_f32_16x16x32_bf16(af[p][i], bfr[p][j], acc[i][j], 0, 0, 0);
    __syncthreads();
  }

  // C/D layout: col = lane&15, row = (lane>>4)*4 + reg  [verified m89/m91]
  const int r0 = bm * 128 + wm + lq * 4;
  const int c0 = bn * 128 + wn + lr;
#pragma unroll
  for (int j = 0; j < 4; j++) {
    const int col = c0 + j * 16;
    const float bv = FUSE_GELU ? bias[col] : 0.f;
#pragma unroll
    for (int i = 0; i < 4; i++) {
      const int row = r0 + i * 16;
#pragma unroll
      for (int r = 0; r < 4; r++) {
        float v = acc[i][j][r];
        if (FUSE_GELU) {
          v += bv;
          v = 0.5f * v * (1.f + erff(v * 0.70710678118654752f));
          Hout[(size_t)(row + r) * N + col] = f2bf(v);
        } else if (ATOMIC) {
          atomicAdd(&Fout[(size_t)(row + r) * N + col], v);
        } else {
          Fout[(size_t)(row + r) * N + col] = v;
        }
      }
    }
  }
}

extern "C" void kernel_launch(void* const* d_in, const int* in_sizes, int n_in,
                              void* d_out, int out_size, void* d_ws, size_t ws_size,
                              hipStream_t stream) {
  const float* x   = (const float*)d_in[0];
  const float* g1a = (const float*)d_in[1];
  const float* g1b = (const float*)d_in[2];
  const float* g1c = (const float*)d_in[3];
  const float* g1d = (const float*)d_in[4];
  const float* b1  = (const float*)d_in[5];
  const float* g2a = (const float*)d_in[6];
  const float* g2b = (const float*)d_in[7];
  const float* g2c = (const float*)d_in[8];
  const float* g2d = (const float*)d_in[9];
  const float* b2  = (const float*)d_in[10];
  float* out = (float*)d_out;

  char* ws = (char*)d_ws;
  u16*  xb     = (u16*)(ws + 0);          // 4096x768 bf16   = 6291456 B
  u16*  W1t    = (u16*)(ws + 6291456);    // 3072x768 bf16   = 4718592 B
  u16*  W2t    = (u16*)(ws + 11010048);   // 768x3072 bf16   = 4718592 B
  u16*  h      = (u16*)(ws + 15728640);   // 4096x3072 bf16  = 25165824 B
  float* B12_1  = (float*)(ws + 40894464);  // 9216 f32
  float* B123_1 = (float*)(ws + 40931328);  // 221184 f32
  float* B12_2  = (float*)(ws + 41816064);  // 9216 f32
  float* B123_2 = (float*)(ws + 41852928);  // 221184 f32

  // x -> bf16, out = bias2 broadcast
  prep<<<3072, 256, 0, stream>>>((const float4*)x, (ushort4*)xb,
                                 (const float4*)b2, (float4*)out, 786432, 192);

  // layer 1: I=(4,4,6,8) O=(4,6,8,16) ranks (12,24,12)
  tt_stage1<<<36, 256, 0, stream>>>(g1a, g1b, B12_1, 4, 4, 6, 12, 24, 9216);
  tt_stage2<<<864, 256, 0, stream>>>(B12_1, g1c, B123_1, 6, 8, 24, 12, 24, 192, 221184);
  tt_stage3v<8><<<1152, 256, 0, stream>>>(B123_1, g1d, W1t, 16, 192, 768, 294912);

  // layer 2: I=(4,6,8,16) O=(4,4,6,8)
  tt_stage1<<<36, 256, 0, stream>>>(g2a, g2b, B12_2, 6, 4, 4, 12, 24, 9216);
  tt_stage2<<<864, 256, 0, stream>>>(B12_2, g2c, B123_2, 8, 6, 24, 12, 16, 96, 221184);
  tt_stage3v<16><<<576, 256, 0, stream>>>(B123_2, g2d, W2t, 8, 96, 3072, 147456);

  // GEMM1: h = gelu(x @ W1 + b1)   (4096 x 3072, K=768), 768 blocks, 12 iters
  gemm_bt<true, false><<<dim3(32, 24, 1), 256, 0, stream>>>(xb, W1t, b1, h, nullptr, 3072, 768, 768);
  // GEMM2: out += h @ W2           (4096 x 768, K=3072 split 4x768), 768 blocks, 12 iters
  gemm_bt<false, true><<<dim3(32, 6, 4), 256, 0, stream>>>(h, W2t, nullptr, nullptr, out, 768, 3072, 768);
}

// Round 4
// 200.177 us; speedup vs baseline: 1.3417x; 1.3417x over previous
//
#include <hip/hip_runtime.h>
#include <cstdint>
#include <cstddef>

typedef unsigned short u16;
typedef __attribute__((ext_vector_type(8))) __bf16 bf16x8;
typedef __attribute__((ext_vector_type(4))) float f32x4;

__device__ __forceinline__ u16 f2bf(float f) {
  unsigned u = __float_as_uint(f);
  u += 0x7FFFu + ((u >> 16) & 1u);   // round-to-nearest-even
  return (u16)(u >> 16);
}

__device__ __forceinline__ float bf2f(u16 h) {
  return __uint_as_float(((unsigned)h) << 16);
}

__device__ __forceinline__ void async16(u16* lds, const u16* g) {
  __builtin_amdgcn_global_load_lds(
      (const __attribute__((address_space(1))) unsigned int*)g,
      (__attribute__((address_space(3))) unsigned int*)lds, 16, 0, 0);
}

// ---------------- TT weight expansion --------------
__global__ void tt_stage1(const float* __restrict__ gA, const float* __restrict__ gB,
                          float* __restrict__ B12,
                          int I2, int O1, int O2, int R1, int R2, int total) {
  int idx = blockIdx.x * 256 + threadIdx.x;
  if (idx >= total) return;
  int r2 = idx % R2; int t = idx / R2;
  int o2 = t % O2; t /= O2;
  int o1 = t % O1; t /= O1;
  int i2 = t % I2; int i1 = t / I2;
  float s = 0.f;
  for (int r1 = 0; r1 < R1; ++r1)
    s += gA[(i1 * O1 + o1) * R1 + r1] * gB[((r1 * I2 + i2) * O2 + o2) * R2 + r2];
  B12[idx] = s;
}

// Writes B123 TRANSPOSED: B123T[(fo123*R3 + r3)*fiCnt + fi123]
// so stage3's rank-reads are lane-coalesced.
__global__ void tt_stage2t(const float* __restrict__ B12, const float* __restrict__ gC,
                           float* __restrict__ B123T,
                           int I3, int O3, int R2, int R3, int O12, int fiCnt, int total) {
  int idx = blockIdx.x * 256 + threadIdx.x;
  if (idx >= total) return;
  int fi = idx % fiCnt; int t = idx / fiCnt;
  int r3 = t % R3; int fo = t / R3;
  int o3 = fo % O3; int fo12 = fo / O3;
  int i3 = fi % I3; int fi12 = fi / I3;
  float s = 0.f;
  for (int r2 = 0; r2 < R2; ++r2)
    s += B12[(fi12 * O12 + fo12) * R2 + r2] * gC[((r2 * I3 + i3) * O3 + o3) * R3 + r3];
  B123T[idx] = s;
}

// Coalesced stage3: thread (out, fi123); B123T reads coalesced across lanes,
// gD (1536 floats) staged in LDS, 16B vector stores.
template <int I4>
__global__ void tt_stage3t(const float* __restrict__ B123T, const float* __restrict__ gD,
                           u16* __restrict__ Wt,
                           int O4, int fiCnt, int Kin, int P) {
  __shared__ float gDs[1536];
  int tid = threadIdx.x;
#pragma unroll
  for (int k = 0; k < 6; ++k) gDs[tid + k * 256] = gD[tid + k * 256];
  __syncthreads();
  int idx = blockIdx.x * 256 + tid;
  if (idx >= P) return;
  int fi123 = idx % fiCnt;
  int out = idx / fiCnt;
  int o4 = out % O4, fo123 = out / O4;
  float b[12];
#pragma unroll
  for (int r = 0; r < 12; ++r)
    b[r] = B123T[(size_t)(fo123 * 12 + r) * fiCnt + fi123];
  u16 vals[I4];
#pragma unroll
  for (int i4 = 0; i4 < I4; ++i4) {
    float s = 0.f;
#pragma unroll
    for (int r = 0; r < 12; ++r)
      s += b[r] * gDs[(r * I4 + i4) * O4 + o4];
    vals[i4] = f2bf(s);
  }
  uint4* dst = (uint4*)(Wt + (size_t)out * Kin + fi123 * I4);
  const uint4* src = (const uint4*)vals;
#pragma unroll
  for (int c = 0; c < I4 / 8; ++c) dst[c] = src[c];
}

__global__ void cvt_f32_bf16(const float4* __restrict__ in, ushort4* __restrict__ out, int n4) {
  int i = blockIdx.x * 256 + threadIdx.x;
  if (i < n4) {
    float4 v = in[i];
    ushort4 o;
    o.x = f2bf(v.x); o.y = f2bf(v.y); o.z = f2bf(v.z); o.w = f2bf(v.w);
    out[i] = o;
  }
}

// out = bias2 + sum of 4 bf16 partials
__global__ void reduce4(const ushort4* __restrict__ P, const float4* __restrict__ b4,
                        float4* __restrict__ out4, int n4, int bn4, int zstride4) {
  int i = blockIdx.x * 256 + threadIdx.x;
  if (i >= n4) return;
  float4 acc = b4[i % bn4];
#pragma unroll
  for (int s = 0; s < 4; ++s) {
    ushort4 u = P[i + s * zstride4];
    acc.x += bf2f(u.x); acc.y += bf2f(u.y); acc.z += bf2f(u.z); acc.w += bf2f(u.w);
  }
  out4[i] = acc;
}

// ---------------- bf16 MFMA GEMM, C = A(MxK) * Bt(NxK)^T, BK=32 (proven) ----------------
// GELU: bias + exact GELU. Else plain. Output always bf16 to Out (+ blockIdx.z*zstride).
template <bool GELU>
__global__ __launch_bounds__(256, 3)
void gemm_bt(const u16* __restrict__ A, const u16* __restrict__ Bt,
             const float* __restrict__ bias, u16* __restrict__ Out,
             int N, int K, int klen, size_t zstride) {
  __shared__ __align__(16) u16 As[128 * 32];
  __shared__ __align__(16) u16 Bs[128 * 32];
  const int tid = threadIdx.x;
  const int bm = blockIdx.x, bn = blockIdx.y;
  const int wave = tid >> 6, lane = tid & 63;
  const int wm = (wave & 1) * 64, wn = (wave >> 1) * 64;
  const int lr = lane & 15, lq = lane >> 4;

  const int srow = tid >> 2;
  const int scol = (tid & 3) * 8;
  const u16* Ag = A + (size_t)(bm * 128 + srow) * K + scol;
  const u16* Bg = Bt + (size_t)(bn * 128 + srow) * K + scol;
  u16* AsW = As + tid * 8;
  u16* BsW = Bs + tid * 8;

  f32x4 acc[4][4];
#pragma unroll
  for (int i = 0; i < 4; i++)
#pragma unroll
    for (int j = 0; j < 4; j++) acc[i][j] = (f32x4){0.f, 0.f, 0.f, 0.f};

  const int kbeg = blockIdx.z * klen;
  const int kend = kbeg + klen;
  for (int k0 = kbeg; k0 < kend; k0 += 32) {
    async16(AsW,        Ag + k0);
    async16(AsW + 2048, Ag + k0 + (size_t)64 * K);
    async16(BsW,        Bg + k0);
    async16(BsW + 2048, Bg + k0 + (size_t)64 * K);
    __syncthreads();
    bf16x8 af[4], bfr[4];
#pragma unroll
    for (int i = 0; i < 4; i++)
      af[i] = *(const bf16x8*)(As + (wm + i * 16 + lr) * 32 + lq * 8);
#pragma unroll
    for (int j = 0; j < 4; j++)
      bfr[j] = *(const bf16x8*)(Bs + (wn + j * 16 + lr) * 32 + lq * 8);
#pragma unroll
    for (int i = 0; i < 4; i++)
#pragma unroll
      for (int j = 0; j < 4; j++)
        acc[i][j] = __builtin_amdgcn_mfma_f32_16x16x32_bf16(af[i], bfr[j], acc[i][j], 0, 0, 0);
    __syncthreads();
  }

  u16* Op = Out + blockIdx.z * zstride;
  // C/D layout: col = lane&15, row = (lane>>4)*4 + reg  [verified m89/m91]
  const int r0 = bm * 128 + wm + lq * 4;
  const int c0 = bn * 128 + wn + lr;
#pragma unroll
  for (int j = 0; j < 4; j++) {
    const int col = c0 + j * 16;
    const float bv = GELU ? bias[col] : 0.f;
#pragma unroll
    for (int i = 0; i < 4; i++) {
      const int row = r0 + i * 16;
#pragma unroll
      for (int r = 0; r < 4; r++) {
        float v = acc[i][j][r];
        if (GELU) {
          v += bv;
          v = 0.5f * v * (1.f + erff(v * 0.70710678118654752f));
        }
        Op[(size_t)(row + r) * N + col] = f2bf(v);
      }
    }
  }
}

extern "C" void kernel_launch(void* const* d_in, const int* in_sizes, int n_in,
                              void* d_out, int out_size, void* d_ws, size_t ws_size,
                              hipStream_t stream) {
  const float* x   = (const float*)d_in[0];
  const float* g1a = (const float*)d_in[1];
  const float* g1b = (const float*)d_in[2];
  const float* g1c = (const float*)d_in[3];
  const float* g1d = (const float*)d_in[4];
  const float* b1  = (const float*)d_in[5];
  const float* g2a = (const float*)d_in[6];
  const float* g2b = (const float*)d_in[7];
  const float* g2c = (const float*)d_in[8];
  const float* g2d = (const float*)d_in[9];
  const float* b2  = (const float*)d_in[10];
  float* out = (float*)d_out;

  char* ws = (char*)d_ws;
  u16*  xb     = (u16*)(ws + 0);          // 4096x768 bf16   = 6291456 B
  u16*  W1t    = (u16*)(ws + 6291456);    // 3072x768 bf16   = 4718592 B
  u16*  W2t    = (u16*)(ws + 11010048);   // 768x3072 bf16   = 4718592 B
  u16*  h      = (u16*)(ws + 15728640);   // 4096x3072 bf16  = 25165824 B
  float* B12_1  = (float*)(ws + 40894464);  // 9216 f32
  float* B123_1 = (float*)(ws + 40931328);  // 221184 f32
  float* B12_2  = (float*)(ws + 41816064);  // 9216 f32
  float* B123_2 = (float*)(ws + 41852928);  // 221184 f32
  u16*  Part   = (u16*)(ws + 42737664);   // 4 x 4096x768 bf16 = 25165824 B (total ws 64.8 MB)

  // x -> bf16
  cvt_f32_bf16<<<3072, 256, 0, stream>>>((const float4*)x, (ushort4*)xb, 786432);

  // layer 1: I=(4,4,6,8) O=(4,6,8,16) ranks (12,24,12); fiCnt=96, O123=192
  tt_stage1<<<36, 256, 0, stream>>>(g1a, g1b, B12_1, 4, 4, 6, 12, 24, 9216);
  tt_stage2t<<<864, 256, 0, stream>>>(B12_1, g1c, B123_1, 6, 8, 24, 12, 24, 96, 221184);
  tt_stage3t<8><<<1152, 256, 0, stream>>>(B123_1, g1d, W1t, 16, 96, 768, 294912);

  // layer 2: I=(4,6,8,16) O=(4,4,6,8); fiCnt=192, O123=96
  tt_stage1<<<36, 256, 0, stream>>>(g2a, g2b, B12_2, 6, 4, 4, 12, 24, 9216);
  tt_stage2t<<<864, 256, 0, stream>>>(B12_2, g2c, B123_2, 8, 6, 24, 12, 16, 192, 221184);
  tt_stage3t<16><<<576, 256, 0, stream>>>(B123_2, g2d, W2t, 8, 192, 3072, 147456);

  // GEMM1: h = gelu(x @ W1 + b1)   (4096 x 3072, K=768), 768 blocks, 3/CU
  gemm_bt<true><<<dim3(32, 24, 1), 256, 0, stream>>>(xb, W1t, b1, h, 3072, 768, 768, 0);
  // GEMM2: bf16 partials, K=3072 split 4x768, 768 blocks, no atomics
  gemm_bt<false><<<dim3(32, 6, 4), 256, 0, stream>>>(h, W2t, nullptr, Part, 768, 3072, 768, 3145728);
  // out = b2 + sum(partials)
  reduce4<<<3072, 256, 0, stream>>>((const ushort4*)Part, (const float4*)b2,
                                    (float4*)out, 786432, 192, 786432);
}